// Round 3
// baseline (5472.007 us; speedup 1.0000x reference)
//
#include <hip/hip_runtime.h>

// Problem constants
// B=16, H=8, W=32, D=512, HID=512, C=7000, T=40 (41 scan steps)
#define NS 41
#define LSTM_NB 64

__device__ __forceinline__ float fsig(float x) { return 1.0f / (1.0f + __expf(-x)); }
__device__ __forceinline__ float ftanhf(float x) {
    float t = __expf(fminf(fmaxf(2.0f * x, -30.0f), 30.0f));
    return 1.0f - 2.0f / (t + 1.0f);
}

// ---------------------------------------------------------------------------
// Generic TN GEMM: C[m,n] = sum_k A[m,k]*B[n,k] (+bias[n]+bias2[n])
// A: M x K (lda), B: N x K (ldb), both K-contiguous.
// ksplit>1: split-K with atomicAdd into pre-zeroed C (no bias applied).
// cmode==2: store to C[(m&15)*280000 + (m>>4)*7000 + n] (final output remap)
// ---------------------------------------------------------------------------
__launch_bounds__(256)
__global__ void gemm_tn(const float* __restrict__ A, const float* __restrict__ B,
                        float* __restrict__ C, int M, int N, int K,
                        int lda, int ldb, int ldc,
                        const float* __restrict__ bias, const float* __restrict__ bias2,
                        int cmode, int ksplit)
{
    __shared__ float As[32][68];
    __shared__ float Bs[32][68];
    const int tid = threadIdx.x;
    const int m0 = blockIdx.x * 64, n0 = blockIdx.y * 64;
    int ck = K, kb0 = 0;
    if (ksplit > 1) {
        ck = (((K + ksplit - 1) / ksplit) + 31) & ~31;
        kb0 = blockIdx.z * ck;
    }
    const int kend = min(K, kb0 + ck);
    float acc[4][4] = {};
    const int ty = tid >> 4, tx = tid & 15;

    for (int kb = kb0; kb < kend; kb += 32) {
#pragma unroll
        for (int j = 0; j < 2; ++j) {
            int i = tid + j * 256;           // float4 slot 0..511
            int ml = i >> 3, kq = i & 7;
            int gm = m0 + ml, gk = kb + kq * 4;
            float4 v = make_float4(0.f, 0.f, 0.f, 0.f);
            if (gm < M) {
                if (gk + 4 <= kend) v = *(const float4*)(A + (size_t)gm * lda + gk);
                else {
                    float tmp[4] = {0.f, 0.f, 0.f, 0.f};
                    for (int e = 0; e < 4; ++e)
                        if (gk + e < kend) tmp[e] = A[(size_t)gm * lda + gk + e];
                    v = make_float4(tmp[0], tmp[1], tmp[2], tmp[3]);
                }
            }
            As[kq * 4 + 0][ml] = v.x; As[kq * 4 + 1][ml] = v.y;
            As[kq * 4 + 2][ml] = v.z; As[kq * 4 + 3][ml] = v.w;
        }
#pragma unroll
        for (int j = 0; j < 2; ++j) {
            int i = tid + j * 256;
            int nl = i >> 3, kq = i & 7;
            int gn = n0 + nl, gk = kb + kq * 4;
            float4 v = make_float4(0.f, 0.f, 0.f, 0.f);
            if (gn < N) {
                if (gk + 4 <= kend) v = *(const float4*)(B + (size_t)gn * ldb + gk);
                else {
                    float tmp[4] = {0.f, 0.f, 0.f, 0.f};
                    for (int e = 0; e < 4; ++e)
                        if (gk + e < kend) tmp[e] = B[(size_t)gn * ldb + gk + e];
                    v = make_float4(tmp[0], tmp[1], tmp[2], tmp[3]);
                }
            }
            Bs[kq * 4 + 0][nl] = v.x; Bs[kq * 4 + 1][nl] = v.y;
            Bs[kq * 4 + 2][nl] = v.z; Bs[kq * 4 + 3][nl] = v.w;
        }
        __syncthreads();
#pragma unroll
        for (int kk = 0; kk < 32; ++kk) {
            float4 a = *(const float4*)&As[kk][ty * 4];
            float4 bv = *(const float4*)&Bs[kk][tx * 4];
            float av[4] = {a.x, a.y, a.z, a.w};
            float bw[4] = {bv.x, bv.y, bv.z, bv.w};
#pragma unroll
            for (int i2 = 0; i2 < 4; ++i2)
#pragma unroll
                for (int j2 = 0; j2 < 4; ++j2)
                    acc[i2][j2] = fmaf(av[i2], bw[j2], acc[i2][j2]);
        }
        __syncthreads();
    }

#pragma unroll
    for (int i2 = 0; i2 < 4; ++i2) {
        int m = m0 + ty * 4 + i2;
        if (m >= M) continue;
#pragma unroll
        for (int j2 = 0; j2 < 4; ++j2) {
            int n = n0 + tx * 4 + j2;
            if (n >= N) continue;
            float v = acc[i2][j2];
            if (ksplit > 1) {
                atomicAdd(&C[(size_t)m * ldc + n], v);
            } else {
                if (bias)  v += bias[n];
                if (bias2) v += bias2[n];
                if (cmode == 2)
                    C[(size_t)(m & 15) * 280000 + (size_t)(m >> 4) * 7000 + n] = v;
                else
                    C[(size_t)m * ldc + n] = v;
            }
        }
    }
}

// ---------------------------------------------------------------------------
// Build xs[t][b][h]: t=0 -> hw; t=1 -> w_lin1[:,C-3]+b; t>=2 -> xs_tf + b
// ---------------------------------------------------------------------------
__launch_bounds__(256)
__global__ void build_xs(const float* __restrict__ hw, const float* __restrict__ xs_tf,
                         const float* __restrict__ w_lin1, const float* __restrict__ b_lin1,
                         float* __restrict__ xs)
{
    int blk = blockIdx.x;
    int t = blk >> 4, b = blk & 15;
    for (int h = threadIdx.x; h < 512; h += 256) {
        float v;
        if (t == 0)      v = hw[b * 512 + h];
        else if (t == 1) v = w_lin1[(size_t)h * 7000 + 6997] + b_lin1[h];
        else             v = xs_tf[((size_t)b * 39 + (t - 2)) * 512 + h] + b_lin1[h];
        xs[((size_t)t * 16 + b) * 512 + h] = v;
    }
}

// ---------------------------------------------------------------------------
// 3x3 SAME conv
// ---------------------------------------------------------------------------
__launch_bounds__(256)
__global__ void conv3x3(const float* __restrict__ V, const float* __restrict__ w2,
                        const float* __restrict__ b2, float* __restrict__ outc)
{
    const int b = blockIdx.y, d0 = blockIdx.x * 8;
    const int tid = threadIdx.x;
    const int h = tid >> 5, w = tid & 31;
    __shared__ float Vs[256];
    float acc[8] = {0.f, 0.f, 0.f, 0.f, 0.f, 0.f, 0.f, 0.f};
    const float* Vb = V + (size_t)b * 512 * 256;
    for (int c = 0; c < 512; ++c) {
        __syncthreads();
        Vs[tid] = Vb[(size_t)c * 256 + tid];
        __syncthreads();
        float v[9];
#pragma unroll
        for (int dh = 0; dh < 3; ++dh)
#pragma unroll
            for (int dw = 0; dw < 3; ++dw) {
                int hh = h + dh - 1, ww = w + dw - 1;
                v[dh * 3 + dw] = (hh >= 0 && hh < 8 && ww >= 0 && ww < 32) ? Vs[hh * 32 + ww] : 0.f;
            }
#pragma unroll
        for (int dl = 0; dl < 8; ++dl) {
            const float* wp = w2 + ((size_t)(d0 + dl) * 512 + c) * 9;
            float a = acc[dl];
            a = fmaf(v[0], wp[0], a); a = fmaf(v[1], wp[1], a); a = fmaf(v[2], wp[2], a);
            a = fmaf(v[3], wp[3], a); a = fmaf(v[4], wp[4], a); a = fmaf(v[5], wp[5], a);
            a = fmaf(v[6], wp[6], a); a = fmaf(v[7], wp[7], a); a = fmaf(v[8], wp[8], a);
            acc[dl] = a;
        }
    }
#pragma unroll
    for (int dl = 0; dl < 8; ++dl)
        outc[((size_t)b * 512 + d0 + dl) * 256 + tid] = acc[dl] + b2[d0 + dl];
}

// ---------------------------------------------------------------------------
// Sequential 2-layer LSTM recurrence, 64 blocks x 1024 threads.
// Barrier redesign (round 3): NO shared-line RMW. Each block posts a
// monotonic phase number to its OWN 128B flag slot (agent-scope store).
// Block 0's wave 0 polls all 64 flag lines (64-lane gather, distinct lines),
// then thread 0 stores the phase to a separate `release` line. Spinners poll
// `release` with s_sleep backoff. Ordering: h-stores are agent-scope
// write-through and are drained by vmcnt(0) inside __syncthreads() BEFORE the
// flag store, so flag>=ph implies that block's h values are at the coherence
// point; release>=ph implies all are. Readers use a fresh buffer slot per
// step so plain loads can never hit a stale cached line.
// ---------------------------------------------------------------------------
__device__ __forceinline__ void gbar2(unsigned* __restrict__ flags,
                                      unsigned* __restrict__ release,
                                      unsigned ph)
{
    __syncthreads();   // all waves done; vmcnt(0) -> h stores acked
    if (blockIdx.x == 0) {
        if (threadIdx.x > 0 && threadIdx.x < 64) {
            while (__hip_atomic_load(&flags[threadIdx.x * 32],
                                     __ATOMIC_RELAXED, __HIP_MEMORY_SCOPE_AGENT) < ph)
                __builtin_amdgcn_s_sleep(4);
        }
        __syncthreads();
        if (threadIdx.x == 0)
            __hip_atomic_store(release, ph, __ATOMIC_RELAXED, __HIP_MEMORY_SCOPE_AGENT);
    } else {
        if (threadIdx.x == 0) {
            __hip_atomic_store(&flags[blockIdx.x * 32], ph,
                               __ATOMIC_RELAXED, __HIP_MEMORY_SCOPE_AGENT);
            while (__hip_atomic_load(release, __ATOMIC_RELAXED,
                                     __HIP_MEMORY_SCOPE_AGENT) < ph)
                __builtin_amdgcn_s_sleep(4);
        }
    }
    __syncthreads();
}

__launch_bounds__(1024)
__global__ void lstm_rec(const float* __restrict__ g1x,
                         const float* __restrict__ Wih,
                         const float* __restrict__ Whh,
                         const float* __restrict__ bih,
                         const float* __restrict__ bhh,
                         float* __restrict__ h1all,   // 42 x 16 x 512
                         float* __restrict__ c1,      // 16 x 512
                         float* __restrict__ c2,      // 16 x 512
                         float* __restrict__ h2all,   // 42 x 16 x 512
                         unsigned* __restrict__ barflags)
{
    const int bk = blockIdx.x;
    const int tid = threadIdx.x;
    const int p = tid & 511, half = tid >> 9;
    const int b = p & 15, ug = p >> 4;        // ug = u_l*4 + q, 0..31
    const int u_l = ug >> 2, q = ug & 3;
    const int u = bk * 8 + u_l;
    const int n = q * 512 + u;
    const float4* wih4 = (const float4*)(Wih + (size_t)n * 512 + half * 256);
    const float4* whh4 = (const float4*)(Whh + (size_t)n * 512 + half * 256);
    const float bsum = bih[n] + bhh[n];
    unsigned* release = barflags + 2048;
    __shared__ float part[1024];
    __shared__ float gfull[512];

    for (int t = 0; t < NS; ++t) {
        // ---- cell 1: g = g1x[t] + h1_old @ Whh^T
        {
            const float4* h1o = (const float4*)(h1all + (size_t)t * 8192 + b * 512 + half * 256);
            float s = 0.f;
#pragma unroll 8
            for (int k = 0; k < 64; ++k) {
                float4 wv = whh4[k], hv = h1o[k];
                s = fmaf(wv.x, hv.x, s); s = fmaf(wv.y, hv.y, s);
                s = fmaf(wv.z, hv.z, s); s = fmaf(wv.w, hv.w, s);
            }
            part[tid] = s;
            __syncthreads();
            if (half == 0)
                gfull[p] = g1x[(size_t)(t * 16 + b) * 2048 + n] + s + part[tid + 512];
            __syncthreads();
            if (tid < 128) {
                int ul2 = tid >> 4, bb = tid & 15;
                int uu = bk * 8 + ul2;
                float gi = gfull[(ul2 * 4 + 0) * 16 + bb];
                float gf = gfull[(ul2 * 4 + 1) * 16 + bb];
                float gg = gfull[(ul2 * 4 + 2) * 16 + bb];
                float go = gfull[(ul2 * 4 + 3) * 16 + bb];
                float cn = fsig(gf) * c1[bb * 512 + uu] + fsig(gi) * ftanhf(gg);
                c1[bb * 512 + uu] = cn;   // block-private: plain store ok
                __hip_atomic_store(&h1all[(size_t)(t + 1) * 8192 + bb * 512 + uu],
                                   fsig(go) * ftanhf(cn),
                                   __ATOMIC_RELAXED, __HIP_MEMORY_SCOPE_AGENT);
            }
        }
        gbar2(barflags, release, (unsigned)(2 * t + 1));
        // ---- cell 2: g = bsum + h1_new @ Wih^T + h2_old @ Whh^T
        {
            const float4* h1n = (const float4*)(h1all + (size_t)(t + 1) * 8192 + b * 512 + half * 256);
            const float4* h2o = (const float4*)(h2all + (size_t)t * 8192 + b * 512 + half * 256);
            float s = 0.f;
#pragma unroll 4
            for (int k = 0; k < 64; ++k) {
                float4 wi = wih4[k], h1v = h1n[k];
                float4 wh = whh4[k], h2v = h2o[k];
                s = fmaf(wi.x, h1v.x, s); s = fmaf(wi.y, h1v.y, s);
                s = fmaf(wi.z, h1v.z, s); s = fmaf(wi.w, h1v.w, s);
                s = fmaf(wh.x, h2v.x, s); s = fmaf(wh.y, h2v.y, s);
                s = fmaf(wh.z, h2v.z, s); s = fmaf(wh.w, h2v.w, s);
            }
            part[tid] = s;
            __syncthreads();
            if (half == 0)
                gfull[p] = bsum + s + part[tid + 512];
            __syncthreads();
            if (tid < 128) {
                int ul2 = tid >> 4, bb = tid & 15;
                int uu = bk * 8 + ul2;
                float gi = gfull[(ul2 * 4 + 0) * 16 + bb];
                float gf = gfull[(ul2 * 4 + 1) * 16 + bb];
                float gg = gfull[(ul2 * 4 + 2) * 16 + bb];
                float go = gfull[(ul2 * 4 + 3) * 16 + bb];
                float cn = fsig(gf) * c2[bb * 512 + uu] + fsig(gi) * ftanhf(gg);
                c2[bb * 512 + uu] = cn;
                __hip_atomic_store(&h2all[(size_t)(t + 1) * 8192 + bb * 512 + uu],
                                   fsig(go) * ftanhf(cn),
                                   __ATOMIC_RELAXED, __HIP_MEMORY_SCOPE_AGENT);
            }
        }
        gbar2(barflags, release, (unsigned)(2 * t + 2));
    }
}

// ---------------------------------------------------------------------------
// Attention: per (to,b): logits = sum_d w3[d]*tanh(conv2V+hproj) + b3,
// softmax over 256 positions -> attw (written to output), glimpse = V @ attw.
// ---------------------------------------------------------------------------
__launch_bounds__(256)
__global__ void attention_k(const float* __restrict__ conv2V, const float* __restrict__ hproj,
                            const float* __restrict__ V, const float* __restrict__ w3,
                            const float* __restrict__ b3, float* __restrict__ attw_out,
                            float* __restrict__ glimpse)
{
    const int r = blockIdx.x;
    const int to = r >> 4, b = r & 15;
    const int tid = threadIdx.x;
    const float* cb = conv2V + (size_t)b * 512 * 256;
    const float* hp = hproj + (size_t)r * 512;
    __shared__ float red[256];
    float acc = 0.f;
#pragma unroll 4
    for (int d = 0; d < 512; ++d) {
        float x = cb[(size_t)d * 256 + tid] + hp[d];
        acc = fmaf(w3[d], ftanhf(x), acc);
    }
    float logit = acc + b3[0];
    red[tid] = logit; __syncthreads();
    for (int s = 128; s > 0; s >>= 1) { if (tid < s) red[tid] = fmaxf(red[tid], red[tid + s]); __syncthreads(); }
    float mx = red[0]; __syncthreads();
    float e = __expf(logit - mx);
    red[tid] = e; __syncthreads();
    for (int s = 128; s > 0; s >>= 1) { if (tid < s) red[tid] += red[tid + s]; __syncthreads(); }
    float aw = e / red[0];
    __syncthreads();
    attw_out[(size_t)b * 10240 + (size_t)to * 256 + tid] = aw;
    red[tid] = aw; __syncthreads();
    const float* Vb = V + (size_t)b * 512 * 256;
#pragma unroll
    for (int dl = 0; dl < 2; ++dl) {
        int d = tid + dl * 256;
        float g = 0.f;
        for (int p4 = 0; p4 < 256; p4 += 4) {
            float4 vv = *(const float4*)(Vb + (size_t)d * 256 + p4);
            g = fmaf(vv.x, red[p4], g);     g = fmaf(vv.y, red[p4 + 1], g);
            g = fmaf(vv.z, red[p4 + 2], g); g = fmaf(vv.w, red[p4 + 3], g);
        }
        glimpse[(size_t)r * 512 + d] = g;
    }
}

// feat[r][k] = k<512 ? h2all[r+32][k] : glimpse[r][k-512];  grid = 2560
__launch_bounds__(256)
__global__ void concat_feat(const float* __restrict__ h2all, const float* __restrict__ glimpse,
                            float* __restrict__ feat)
{
    int idx = blockIdx.x * 256 + threadIdx.x;
    int r = idx >> 10, k = idx & 1023;
    feat[idx] = (k < 512) ? h2all[(size_t)(r + 32) * 512 + k]
                          : glimpse[(size_t)r * 512 + (k - 512)];
}

// In-place log_softmax over rows of 7000 in the final output. grid = 640
__launch_bounds__(256)
__global__ void logsoftmax_k(float* __restrict__ out)
{
    int r = blockIdx.x;
    int b = r & 15, to = r >> 4;
    float* row = out + (size_t)b * 280000 + (size_t)to * 7000;
    __shared__ float buf[7000];
    __shared__ float red[256];
    int tid = threadIdx.x;
    float mx = -1e30f;
    for (int i = tid; i < 7000; i += 256) { float v = row[i]; buf[i] = v; mx = fmaxf(mx, v); }
    red[tid] = mx; __syncthreads();
    for (int s = 128; s > 0; s >>= 1) { if (tid < s) red[tid] = fmaxf(red[tid], red[tid + s]); __syncthreads(); }
    mx = red[0]; __syncthreads();
    float sm = 0.f;
    for (int i = tid; i < 7000; i += 256) sm += __expf(buf[i] - mx);
    red[tid] = sm; __syncthreads();
    for (int s = 128; s > 0; s >>= 1) { if (tid < s) red[tid] += red[tid + s]; __syncthreads(); }
    float lse = mx + __logf(red[0]);
    for (int i = tid; i < 7000; i += 256) row[i] = buf[i] - lse;
}

// ---------------------------------------------------------------------------
extern "C" void kernel_launch(void* const* d_in, const int* in_sizes, int n_in,
                              void* d_out, int out_size, void* d_ws, size_t ws_size,
                              hipStream_t stream)
{
    const float* hw      = (const float*)d_in[0];
    const float* y       = (const float*)d_in[1];
    const float* V       = (const float*)d_in[2];
    const float* w_lin1  = (const float*)d_in[3];
    const float* b_lin1  = (const float*)d_in[4];
    const float* W_ih    = (const float*)d_in[5];
    const float* b_ih    = (const float*)d_in[6];
    const float* W_hh    = (const float*)d_in[7];
    const float* b_hh    = (const float*)d_in[8];
    const float* w_conv1 = (const float*)d_in[9];
    const float* b_conv1 = (const float*)d_in[10];
    const float* w_conv2 = (const float*)d_in[11];
    const float* b_conv2 = (const float*)d_in[12];
    const float* w_conv3 = (const float*)d_in[13];
    const float* b_conv3 = (const float*)d_in[14];
    const float* w_lin2  = (const float*)d_in[15];
    const float* b_lin2  = (const float*)d_in[16];
    float* out = (float*)d_out;

    float* ws = (float*)d_ws;
    float* xs_tf   = ws + 0;            // 624*512   = 319488
    unsigned* barflags = (unsigned*)(ws + 319488);  // 4096 uints (flags[2048] + release)
    float* c1      = ws + 323584;       // 8192
    float* c2      = ws + 331776;       // 8192
    float* h1all   = ws + 339968;       // 42*8192   = 344064
    float* h2all   = ws + 684032;       // 42*8192   = 344064
    float* xs      = ws + 1028096;      // 656*512   = 335872
    float* g1x     = ws + 1363968;      // 656*2048  = 1343488
    float* conv2V  = ws + 2707456;      // 16*512*256= 2097152
    float* hproj   = ws + 4804608;      // 640*512   = 327680
    float* glimpse = ws + 5132288;      // 640*512   = 327680
    float* feat    = ws + 5459968;      // 640*1024  = 655360  -> end 6115328

    // zero: xs_tf (split-K accum) + barflags + c1 + c2 + h1all slot 0; h2all slot 0
    hipMemsetAsync(ws, 0, (size_t)348160 * sizeof(float), stream);
    hipMemsetAsync(ws + 684032, 0, (size_t)8192 * sizeof(float), stream);

    // xs_tf = y @ w_lin1^T   (624 x 512, K=7000, split-K=8)
    gemm_tn<<<dim3(10, 8, 8), 256, 0, stream>>>(y, w_lin1, xs_tf, 624, 512, 7000,
                                                7000, 7000, 512, nullptr, nullptr, 0, 8);
    // xs[41][16][512]
    build_xs<<<656, 256, 0, stream>>>(hw, xs_tf, w_lin1, b_lin1, xs);
    // g1x = xs @ W_ih^T + b_ih + b_hh   (656 x 2048, K=512)
    gemm_tn<<<dim3(11, 32, 1), 256, 0, stream>>>(xs, W_ih, g1x, 656, 2048, 512,
                                                 512, 512, 2048, b_ih, b_hh, 0, 1);
    // conv2V = conv3x3(V) + b_conv2
    conv3x3<<<dim3(64, 16), 256, 0, stream>>>(V, w_conv2, b_conv2, conv2V);

    // sequential recurrence (cooperative launch for co-residency; custom barrier)
    void* args[] = {(void*)&g1x, (void*)&W_ih, (void*)&W_hh, (void*)&b_ih, (void*)&b_hh,
                    (void*)&h1all, (void*)&c1, (void*)&c2, (void*)&h2all, (void*)&barflags};
    hipLaunchCooperativeKernel((void*)lstm_rec, dim3(LSTM_NB), dim3(1024), args, 0, stream);

    // hproj = h2[steps 1..40] @ w1^T + b_conv1   (640 x 512, K=512)
    gemm_tn<<<dim3(10, 8, 1), 256, 0, stream>>>(h2all + 2 * 8192, w_conv1, hproj,
                                                640, 512, 512, 512, 512, 512,
                                                b_conv1, nullptr, 0, 1);
    // attention + glimpse (writes attw directly to output region)
    attention_k<<<640, 256, 0, stream>>>(conv2V, hproj, V, w_conv3, b_conv3,
                                         out + 4480000, glimpse);
    // feat = [h2 | glimpse]
    concat_feat<<<2560, 256, 0, stream>>>(h2all, glimpse, feat);
    // logits = feat @ w_lin2^T + b_lin2 -> out (remapped), then in-place log_softmax
    gemm_tn<<<dim3(10, 110, 1), 256, 0, stream>>>(feat, w_lin2, out, 640, 7000, 1024,
                                                  1024, 1024, 7000, b_lin2, nullptr, 2, 1);
    logsoftmax_k<<<640, 256, 0, stream>>>(out);
}

// Round 4
// 1725.003 us; speedup vs baseline: 3.1722x; 3.1722x over previous
//
#include <hip/hip_runtime.h>

// Problem constants
// B=16, H=8, W=32, D=512, HID=512, C=7000, T=40 (41 scan steps)
#define NS 41
#define LSTM_NB 64

__device__ __forceinline__ float fsig(float x) { return 1.0f / (1.0f + __expf(-x)); }
__device__ __forceinline__ float ftanhf(float x) {
    float t = __expf(fminf(fmaxf(2.0f * x, -30.0f), 30.0f));
    return 1.0f - 2.0f / (t + 1.0f);
}

// ---------------------------------------------------------------------------
// Generic TN GEMM: C[m,n] = sum_k A[m,k]*B[n,k] (+bias[n]+bias2[n])
// ---------------------------------------------------------------------------
__launch_bounds__(256)
__global__ void gemm_tn(const float* __restrict__ A, const float* __restrict__ B,
                        float* __restrict__ C, int M, int N, int K,
                        int lda, int ldb, int ldc,
                        const float* __restrict__ bias, const float* __restrict__ bias2,
                        int cmode, int ksplit)
{
    __shared__ float As[32][68];
    __shared__ float Bs[32][68];
    const int tid = threadIdx.x;
    const int m0 = blockIdx.x * 64, n0 = blockIdx.y * 64;
    int ck = K, kb0 = 0;
    if (ksplit > 1) {
        ck = (((K + ksplit - 1) / ksplit) + 31) & ~31;
        kb0 = blockIdx.z * ck;
    }
    const int kend = min(K, kb0 + ck);
    float acc[4][4] = {};
    const int ty = tid >> 4, tx = tid & 15;

    for (int kb = kb0; kb < kend; kb += 32) {
#pragma unroll
        for (int j = 0; j < 2; ++j) {
            int i = tid + j * 256;
            int ml = i >> 3, kq = i & 7;
            int gm = m0 + ml, gk = kb + kq * 4;
            float4 v = make_float4(0.f, 0.f, 0.f, 0.f);
            if (gm < M) {
                if (gk + 4 <= kend) v = *(const float4*)(A + (size_t)gm * lda + gk);
                else {
                    float tmp[4] = {0.f, 0.f, 0.f, 0.f};
                    for (int e = 0; e < 4; ++e)
                        if (gk + e < kend) tmp[e] = A[(size_t)gm * lda + gk + e];
                    v = make_float4(tmp[0], tmp[1], tmp[2], tmp[3]);
                }
            }
            As[kq * 4 + 0][ml] = v.x; As[kq * 4 + 1][ml] = v.y;
            As[kq * 4 + 2][ml] = v.z; As[kq * 4 + 3][ml] = v.w;
        }
#pragma unroll
        for (int j = 0; j < 2; ++j) {
            int i = tid + j * 256;
            int nl = i >> 3, kq = i & 7;
            int gn = n0 + nl, gk = kb + kq * 4;
            float4 v = make_float4(0.f, 0.f, 0.f, 0.f);
            if (gn < N) {
                if (gk + 4 <= kend) v = *(const float4*)(B + (size_t)gn * ldb + gk);
                else {
                    float tmp[4] = {0.f, 0.f, 0.f, 0.f};
                    for (int e = 0; e < 4; ++e)
                        if (gk + e < kend) tmp[e] = B[(size_t)gn * ldb + gk + e];
                    v = make_float4(tmp[0], tmp[1], tmp[2], tmp[3]);
                }
            }
            Bs[kq * 4 + 0][nl] = v.x; Bs[kq * 4 + 1][nl] = v.y;
            Bs[kq * 4 + 2][nl] = v.z; Bs[kq * 4 + 3][nl] = v.w;
        }
        __syncthreads();
#pragma unroll
        for (int kk = 0; kk < 32; ++kk) {
            float4 a = *(const float4*)&As[kk][ty * 4];
            float4 bv = *(const float4*)&Bs[kk][tx * 4];
            float av[4] = {a.x, a.y, a.z, a.w};
            float bw[4] = {bv.x, bv.y, bv.z, bv.w};
#pragma unroll
            for (int i2 = 0; i2 < 4; ++i2)
#pragma unroll
                for (int j2 = 0; j2 < 4; ++j2)
                    acc[i2][j2] = fmaf(av[i2], bw[j2], acc[i2][j2]);
        }
        __syncthreads();
    }

#pragma unroll
    for (int i2 = 0; i2 < 4; ++i2) {
        int m = m0 + ty * 4 + i2;
        if (m >= M) continue;
#pragma unroll
        for (int j2 = 0; j2 < 4; ++j2) {
            int n = n0 + tx * 4 + j2;
            if (n >= N) continue;
            float v = acc[i2][j2];
            if (ksplit > 1) {
                atomicAdd(&C[(size_t)m * ldc + n], v);
            } else {
                if (bias)  v += bias[n];
                if (bias2) v += bias2[n];
                if (cmode == 2)
                    C[(size_t)(m & 15) * 280000 + (size_t)(m >> 4) * 7000 + n] = v;
                else
                    C[(size_t)m * ldc + n] = v;
            }
        }
    }
}

// ---------------------------------------------------------------------------
__launch_bounds__(256)
__global__ void build_xs(const float* __restrict__ hw, const float* __restrict__ xs_tf,
                         const float* __restrict__ w_lin1, const float* __restrict__ b_lin1,
                         float* __restrict__ xs)
{
    int blk = blockIdx.x;
    int t = blk >> 4, b = blk & 15;
    for (int h = threadIdx.x; h < 512; h += 256) {
        float v;
        if (t == 0)      v = hw[b * 512 + h];
        else if (t == 1) v = w_lin1[(size_t)h * 7000 + 6997] + b_lin1[h];
        else             v = xs_tf[((size_t)b * 39 + (t - 2)) * 512 + h] + b_lin1[h];
        xs[((size_t)t * 16 + b) * 512 + h] = v;
    }
}

// ---------------------------------------------------------------------------
__launch_bounds__(256)
__global__ void conv3x3(const float* __restrict__ V, const float* __restrict__ w2,
                        const float* __restrict__ b2, float* __restrict__ outc)
{
    const int b = blockIdx.y, d0 = blockIdx.x * 8;
    const int tid = threadIdx.x;
    const int h = tid >> 5, w = tid & 31;
    __shared__ float Vs[256];
    float acc[8] = {0.f, 0.f, 0.f, 0.f, 0.f, 0.f, 0.f, 0.f};
    const float* Vb = V + (size_t)b * 512 * 256;
    for (int c = 0; c < 512; ++c) {
        __syncthreads();
        Vs[tid] = Vb[(size_t)c * 256 + tid];
        __syncthreads();
        float v[9];
#pragma unroll
        for (int dh = 0; dh < 3; ++dh)
#pragma unroll
            for (int dw = 0; dw < 3; ++dw) {
                int hh = h + dh - 1, ww = w + dw - 1;
                v[dh * 3 + dw] = (hh >= 0 && hh < 8 && ww >= 0 && ww < 32) ? Vs[hh * 32 + ww] : 0.f;
            }
#pragma unroll
        for (int dl = 0; dl < 8; ++dl) {
            const float* wp = w2 + ((size_t)(d0 + dl) * 512 + c) * 9;
            float a = acc[dl];
            a = fmaf(v[0], wp[0], a); a = fmaf(v[1], wp[1], a); a = fmaf(v[2], wp[2], a);
            a = fmaf(v[3], wp[3], a); a = fmaf(v[4], wp[4], a); a = fmaf(v[5], wp[5], a);
            a = fmaf(v[6], wp[6], a); a = fmaf(v[7], wp[7], a); a = fmaf(v[8], wp[8], a);
            acc[dl] = a;
        }
    }
#pragma unroll
    for (int dl = 0; dl < 8; ++dl)
        outc[((size_t)b * 512 + d0 + dl) * 256 + tid] = acc[dl] + b2[d0 + dl];
}

// ---------------------------------------------------------------------------
// LSTM recurrence, pipelined: phase k computes {cell1(k) || cell2(k-1)},
// one global barrier per phase (42 phases). h staged in LDS (padded rows),
// c-state in LDS, weights from (XCD-local) L2. h exchange: agent-scope
// stores + fresh slot per step (proven protocol from r2/r3).
// ---------------------------------------------------------------------------
__device__ __forceinline__ void gbar2(unsigned* __restrict__ flags,
                                      unsigned* __restrict__ release,
                                      unsigned ph)
{
    __syncthreads();   // all waves done; vmcnt(0) -> h stores acked
    if (blockIdx.x == 0) {
        if (threadIdx.x > 0 && threadIdx.x < 64) {
            while (__hip_atomic_load(&flags[threadIdx.x * 32],
                                     __ATOMIC_RELAXED, __HIP_MEMORY_SCOPE_AGENT) < ph)
                __builtin_amdgcn_s_sleep(2);
        }
        __syncthreads();
        if (threadIdx.x == 0)
            __hip_atomic_store(release, ph, __ATOMIC_RELAXED, __HIP_MEMORY_SCOPE_AGENT);
    } else {
        if (threadIdx.x == 0) {
            __hip_atomic_store(&flags[blockIdx.x * 32], ph,
                               __ATOMIC_RELAXED, __HIP_MEMORY_SCOPE_AGENT);
            while (__hip_atomic_load(release, __ATOMIC_RELAXED,
                                     __HIP_MEMORY_SCOPE_AGENT) < ph)
                __builtin_amdgcn_s_sleep(2);
        }
    }
    __syncthreads();
}

// LDS layout (floats): Hs1[16*516] Hs2[16*516] P1[1024] P2[1024] G1S[512]
//                      C1S[128] C2S[128]  -> 19328 floats = 77312 B (dynamic)
#define HS1_OFF 0
#define HS2_OFF 8256
#define P1_OFF  16512
#define P2_OFF  17536
#define G1S_OFF 18560
#define C1S_OFF 19072
#define C2S_OFF 19200
#define LSTM_LDS_FLOATS 19328

__launch_bounds__(1024, 1)
__global__ void lstm_rec(const float* __restrict__ g1x,
                         const float* __restrict__ Wih,
                         const float* __restrict__ Whh,
                         const float* __restrict__ bih,
                         const float* __restrict__ bhh,
                         float* __restrict__ h1all,   // 42 x 16 x 512
                         float* __restrict__ h2all,   // 42 x 16 x 512
                         unsigned* __restrict__ barflags)
{
    extern __shared__ float sh[];
    float* Hs1 = sh + HS1_OFF;
    float* Hs2 = sh + HS2_OFF;
    float* P1  = sh + P1_OFF;
    float* P2  = sh + P2_OFF;
    float* G1S = sh + G1S_OFF;
    float* C1S = sh + C1S_OFF;
    float* C2S = sh + C2S_OFF;

    const int bk = blockIdx.x;
    const int tid = threadIdx.x;
    const int p = tid & 511, half = tid >> 9;
    const int b = p & 15, ug = p >> 4;        // ug = u_l*4 + q
    const int u_l = ug >> 2, q = ug & 3;
    const int n = q * 512 + bk * 8 + u_l;
    const float4* wih4 = (const float4*)(Wih + (size_t)n * 512 + half * 256);
    const float4* whh4 = (const float4*)(Whh + (size_t)n * 512 + half * 256);
    const float4* hs1v = (const float4*)(Hs1 + b * 516 + half * 256);
    const float4* hs2v = (const float4*)(Hs2 + b * 516 + half * 256);
    unsigned* release = barflags + 2048;

    // finisher constants (cell2 bias sums)
    float bs0 = 0.f, bs1 = 0.f, bs2 = 0.f, bs3 = 0.f;
    if (tid >= 128 && tid < 256) {
        int r = tid - 128, uuf = bk * 8 + (r >> 4);
        bs0 = bih[0 * 512 + uuf] + bhh[0 * 512 + uuf];
        bs1 = bih[1 * 512 + uuf] + bhh[1 * 512 + uuf];
        bs2 = bih[2 * 512 + uuf] + bhh[2 * 512 + uuf];
        bs3 = bih[3 * 512 + uuf] + bhh[3 * 512 + uuf];
    }
    if (tid < 128) { C1S[tid] = 0.f; C2S[tid] = 0.f; }

    // staging indices: 8 consecutive floats per thread
    const int e0 = tid * 8;
    const int sb = e0 >> 9, sj = e0 & 511;

    for (int k = 0; k <= NS; ++k) {           // 42 phases
        const bool doC1 = (k < NS);
        const bool doC2 = (k > 0);
        // ---- stage h (and g1x) into LDS
        {
            const float4* s1 = (const float4*)(h1all + (size_t)k * 8192 + e0);
            float4 a0 = s1[0], a1 = s1[1];
            *(float4*)(Hs1 + sb * 516 + sj) = a0;
            *(float4*)(Hs1 + sb * 516 + sj + 4) = a1;
            if (doC2) {
                const float4* s2 = (const float4*)(h2all + (size_t)(k - 1) * 8192 + e0);
                float4 b0 = s2[0], b1 = s2[1];
                *(float4*)(Hs2 + sb * 516 + sj) = b0;
                *(float4*)(Hs2 + sb * 516 + sj + 4) = b1;
            }
            if (doC1 && tid < 512)
                G1S[tid] = g1x[(size_t)(k * 16 + b) * 2048 + n];
        }
        __syncthreads();
        // ---- partial dots (2 threads per dot, split on K)
        if (doC1 && doC2) {
            float s1 = 0.f, s2a = 0.f, s2b = 0.f;
#pragma unroll 4
            for (int kk = 0; kk < 64; ++kk) {
                float4 wh = whh4[kk], wi = wih4[kk];
                float4 h1v = hs1v[kk], h2v = hs2v[kk];
                s1  = fmaf(wh.x, h1v.x, s1);  s1  = fmaf(wh.y, h1v.y, s1);
                s1  = fmaf(wh.z, h1v.z, s1);  s1  = fmaf(wh.w, h1v.w, s1);
                s2a = fmaf(wi.x, h1v.x, s2a); s2a = fmaf(wi.y, h1v.y, s2a);
                s2a = fmaf(wi.z, h1v.z, s2a); s2a = fmaf(wi.w, h1v.w, s2a);
                s2b = fmaf(wh.x, h2v.x, s2b); s2b = fmaf(wh.y, h2v.y, s2b);
                s2b = fmaf(wh.z, h2v.z, s2b); s2b = fmaf(wh.w, h2v.w, s2b);
            }
            P1[tid] = s1; P2[tid] = s2a + s2b;
        } else if (doC1) {
            float s1 = 0.f;
#pragma unroll 8
            for (int kk = 0; kk < 64; ++kk) {
                float4 wh = whh4[kk], h1v = hs1v[kk];
                s1 = fmaf(wh.x, h1v.x, s1); s1 = fmaf(wh.y, h1v.y, s1);
                s1 = fmaf(wh.z, h1v.z, s1); s1 = fmaf(wh.w, h1v.w, s1);
            }
            P1[tid] = s1;
        } else {
            float s2a = 0.f, s2b = 0.f;
#pragma unroll 4
            for (int kk = 0; kk < 64; ++kk) {
                float4 wi = wih4[kk], wh = whh4[kk];
                float4 h1v = hs1v[kk], h2v = hs2v[kk];
                s2a = fmaf(wi.x, h1v.x, s2a); s2a = fmaf(wi.y, h1v.y, s2a);
                s2a = fmaf(wi.z, h1v.z, s2a); s2a = fmaf(wi.w, h1v.w, s2a);
                s2b = fmaf(wh.x, h2v.x, s2b); s2b = fmaf(wh.y, h2v.y, s2b);
                s2b = fmaf(wh.z, h2v.z, s2b); s2b = fmaf(wh.w, h2v.w, s2b);
            }
            P2[tid] = s2a + s2b;
        }
        __syncthreads();
        // ---- finish: cell1 on waves 0-1, cell2 on waves 2-3 (concurrent)
        if (tid < 128) {
            if (doC1) {
                int bb = tid & 15, uu = bk * 8 + (tid >> 4);
                int p0 = bb + 16 * ((tid >> 4) * 4);
                float gi = G1S[p0]      + P1[p0]      + P1[p0 + 512];
                float gf = G1S[p0 + 16] + P1[p0 + 16] + P1[p0 + 528];
                float gg = G1S[p0 + 32] + P1[p0 + 32] + P1[p0 + 544];
                float go = G1S[p0 + 48] + P1[p0 + 48] + P1[p0 + 560];
                float cn = fsig(gf) * C1S[tid] + fsig(gi) * ftanhf(gg);
                C1S[tid] = cn;
                __hip_atomic_store(&h1all[(size_t)(k + 1) * 8192 + bb * 512 + uu],
                                   fsig(go) * ftanhf(cn),
                                   __ATOMIC_RELAXED, __HIP_MEMORY_SCOPE_AGENT);
            }
        } else if (tid < 256) {
            if (doC2) {
                int r = tid - 128;
                int bb = r & 15, uu = bk * 8 + (r >> 4);
                int p0 = bb + 16 * ((r >> 4) * 4);
                float gi = bs0 + P2[p0]      + P2[p0 + 512];
                float gf = bs1 + P2[p0 + 16] + P2[p0 + 528];
                float gg = bs2 + P2[p0 + 32] + P2[p0 + 544];
                float go = bs3 + P2[p0 + 48] + P2[p0 + 560];
                float cn = fsig(gf) * C2S[r] + fsig(gi) * ftanhf(gg);
                C2S[r] = cn;
                __hip_atomic_store(&h2all[(size_t)k * 8192 + bb * 512 + uu],
                                   fsig(go) * ftanhf(cn),
                                   __ATOMIC_RELAXED, __HIP_MEMORY_SCOPE_AGENT);
            }
        }
        gbar2(barflags, release, (unsigned)(k + 1));
    }
}

// ---------------------------------------------------------------------------
__launch_bounds__(256)
__global__ void attention_k(const float* __restrict__ conv2V, const float* __restrict__ hproj,
                            const float* __restrict__ V, const float* __restrict__ w3,
                            const float* __restrict__ b3, float* __restrict__ attw_out,
                            float* __restrict__ glimpse)
{
    const int r = blockIdx.x;
    const int to = r >> 4, b = r & 15;
    const int tid = threadIdx.x;
    const float* cb = conv2V + (size_t)b * 512 * 256;
    const float* hp = hproj + (size_t)r * 512;
    __shared__ float red[256];
    float acc = 0.f;
#pragma unroll 4
    for (int d = 0; d < 512; ++d) {
        float x = cb[(size_t)d * 256 + tid] + hp[d];
        acc = fmaf(w3[d], ftanhf(x), acc);
    }
    float logit = acc + b3[0];
    red[tid] = logit; __syncthreads();
    for (int s = 128; s > 0; s >>= 1) { if (tid < s) red[tid] = fmaxf(red[tid], red[tid + s]); __syncthreads(); }
    float mx = red[0]; __syncthreads();
    float e = __expf(logit - mx);
    red[tid] = e; __syncthreads();
    for (int s = 128; s > 0; s >>= 1) { if (tid < s) red[tid] += red[tid + s]; __syncthreads(); }
    float aw = e / red[0];
    __syncthreads();
    attw_out[(size_t)b * 10240 + (size_t)to * 256 + tid] = aw;
    red[tid] = aw; __syncthreads();
    const float* Vb = V + (size_t)b * 512 * 256;
#pragma unroll
    for (int dl = 0; dl < 2; ++dl) {
        int d = tid + dl * 256;
        float g = 0.f;
        for (int p4 = 0; p4 < 256; p4 += 4) {
            float4 vv = *(const float4*)(Vb + (size_t)d * 256 + p4);
            g = fmaf(vv.x, red[p4], g);     g = fmaf(vv.y, red[p4 + 1], g);
            g = fmaf(vv.z, red[p4 + 2], g); g = fmaf(vv.w, red[p4 + 3], g);
        }
        glimpse[(size_t)r * 512 + d] = g;
    }
}

// feat[r][k] = k<512 ? h2all[r+32][k] : glimpse[r][k-512];  grid = 2560
__launch_bounds__(256)
__global__ void concat_feat(const float* __restrict__ h2all, const float* __restrict__ glimpse,
                            float* __restrict__ feat)
{
    int idx = blockIdx.x * 256 + threadIdx.x;
    int r = idx >> 10, k = idx & 1023;
    feat[idx] = (k < 512) ? h2all[(size_t)(r + 32) * 512 + k]
                          : glimpse[(size_t)r * 512 + (k - 512)];
}

// In-place log_softmax over rows of 7000 in the final output. grid = 640
__launch_bounds__(256)
__global__ void logsoftmax_k(float* __restrict__ out)
{
    int r = blockIdx.x;
    int b = r & 15, to = r >> 4;
    float* row = out + (size_t)b * 280000 + (size_t)to * 7000;
    __shared__ float buf[7000];
    __shared__ float red[256];
    int tid = threadIdx.x;
    float mx = -1e30f;
    for (int i = tid; i < 7000; i += 256) { float v = row[i]; buf[i] = v; mx = fmaxf(mx, v); }
    red[tid] = mx; __syncthreads();
    for (int s = 128; s > 0; s >>= 1) { if (tid < s) red[tid] = fmaxf(red[tid], red[tid + s]); __syncthreads(); }
    mx = red[0]; __syncthreads();
    float sm = 0.f;
    for (int i = tid; i < 7000; i += 256) sm += __expf(buf[i] - mx);
    red[tid] = sm; __syncthreads();
    for (int s = 128; s > 0; s >>= 1) { if (tid < s) red[tid] += red[tid + s]; __syncthreads(); }
    float lse = mx + __logf(red[0]);
    for (int i = tid; i < 7000; i += 256) row[i] = buf[i] - lse;
}

// ---------------------------------------------------------------------------
extern "C" void kernel_launch(void* const* d_in, const int* in_sizes, int n_in,
                              void* d_out, int out_size, void* d_ws, size_t ws_size,
                              hipStream_t stream)
{
    const float* hw      = (const float*)d_in[0];
    const float* y       = (const float*)d_in[1];
    const float* V       = (const float*)d_in[2];
    const float* w_lin1  = (const float*)d_in[3];
    const float* b_lin1  = (const float*)d_in[4];
    const float* W_ih    = (const float*)d_in[5];
    const float* b_ih    = (const float*)d_in[6];
    const float* W_hh    = (const float*)d_in[7];
    const float* b_hh    = (const float*)d_in[8];
    const float* w_conv1 = (const float*)d_in[9];
    const float* b_conv1 = (const float*)d_in[10];
    const float* w_conv2 = (const float*)d_in[11];
    const float* b_conv2 = (const float*)d_in[12];
    const float* w_conv3 = (const float*)d_in[13];
    const float* b_conv3 = (const float*)d_in[14];
    const float* w_lin2  = (const float*)d_in[15];
    const float* b_lin2  = (const float*)d_in[16];
    float* out = (float*)d_out;

    float* ws = (float*)d_ws;
    float* xs_tf   = ws + 0;                        // 319488
    unsigned* barflags = (unsigned*)(ws + 319488);  // 4096 uints
    float* h1all   = ws + 323584;                   // 42*8192 = 344064
    float* h2all   = ws + 667648;                   // 344064
    float* xs      = ws + 1011712;                  // 335872
    float* g1x     = ws + 1347584;                  // 1343488
    float* conv2V  = ws + 2691072;                  // 2097152
    float* hproj   = ws + 4788224;                  // 327680
    float* glimpse = ws + 5115904;                  // 327680
    float* feat    = ws + 5443584;                  // 655360 -> end 6098944

    // zero: xs_tf + barflags + h1all slot0 ; h2all slot0
    hipMemsetAsync(ws, 0, (size_t)331776 * sizeof(float), stream);
    hipMemsetAsync(ws + 667648, 0, (size_t)8192 * sizeof(float), stream);

    // xs_tf = y @ w_lin1^T   (624 x 512, K=7000, split-K=8)
    gemm_tn<<<dim3(10, 8, 8), 256, 0, stream>>>(y, w_lin1, xs_tf, 624, 512, 7000,
                                                7000, 7000, 512, nullptr, nullptr, 0, 8);
    build_xs<<<656, 256, 0, stream>>>(hw, xs_tf, w_lin1, b_lin1, xs);
    // g1x = xs @ W_ih^T + b_ih + b_hh   (656 x 2048, K=512)
    gemm_tn<<<dim3(11, 32, 1), 256, 0, stream>>>(xs, W_ih, g1x, 656, 2048, 512,
                                                 512, 512, 2048, b_ih, b_hh, 0, 1);
    conv3x3<<<dim3(64, 16), 256, 0, stream>>>(V, w_conv2, b_conv2, conv2V);

    // sequential recurrence (cooperative, 42 pipelined phases, dynamic LDS)
    static bool attr_set = false;
    if (!attr_set) {
        hipFuncSetAttribute((const void*)lstm_rec,
                            hipFuncAttributeMaxDynamicSharedMemorySize,
                            LSTM_LDS_FLOATS * 4);
        attr_set = true;
    }
    void* args[] = {(void*)&g1x, (void*)&W_ih, (void*)&W_hh, (void*)&b_ih, (void*)&b_hh,
                    (void*)&h1all, (void*)&h2all, (void*)&barflags};
    hipLaunchCooperativeKernel((void*)lstm_rec, dim3(LSTM_NB), dim3(1024), args,
                               LSTM_LDS_FLOATS * 4, stream);

    // hproj = h2[steps 1..40] @ w1^T + b_conv1   (640 x 512, K=512)
    gemm_tn<<<dim3(10, 8, 1), 256, 0, stream>>>(h2all + 2 * 8192, w_conv1, hproj,
                                                640, 512, 512, 512, 512, 512,
                                                b_conv1, nullptr, 0, 1);
    attention_k<<<640, 256, 0, stream>>>(conv2V, hproj, V, w_conv3, b_conv3,
                                         out + 4480000, glimpse);
    concat_feat<<<2560, 256, 0, stream>>>(h2all, glimpse, feat);
    gemm_tn<<<dim3(10, 110, 1), 256, 0, stream>>>(feat, w_lin2, out, 640, 7000, 1024,
                                                  1024, 1024, 7000, b_lin2, nullptr, 2, 1);
    logsoftmax_k<<<640, 256, 0, stream>>>(out);
}